// Round 13
// baseline (194.396 us; speedup 1.0000x reference)
//
#include <hip/hip_runtime.h>
#include <hip/hip_bf16.h>
#include <math.h>

#define NN 512
#define VN 40
#define NF 32
#define EFD 4
#define OUTD 128
#define EMAX 96     // max directed edges per graph (<= 90 actual)
#define DMAX 8      // max in-degree
#define MSTR 136    // LDS row stride (shorts) for 128-wide MFMA A-operands
#define WPSTR 104   // row stride (shorts) for 96-wide (68-padded) operands
#define NT 1024     // k_mp threads (16 waves)
#define NW 16

typedef __attribute__((ext_vector_type(8))) short short8;
typedef __attribute__((ext_vector_type(4))) float f32x4;

// tanh(x) = 1 - 2/(exp(2x)+1)
__device__ __forceinline__ float fast_tanh(float x) {
    return fmaf(-2.0f, __builtin_amdgcn_rcpf(__expf(2.0f * x) + 1.0f), 1.0f);
}

// Setup: [0,nbO): off boundaries | [nbO,+nbK): eoff boundaries | [+128): weight conv
__global__ __launch_bounds__(256) void k_setup(
    const int* __restrict__ igeb, const int* __restrict__ eb_b,
    const float* __restrict__ W_att, const float* __restrict__ W_emb,
    const float* __restrict__ Wg_att, const float* __restrict__ Wg_emb,
    const float* __restrict__ W_pre,
    int* __restrict__ off, int* __restrict__ eoff,
    __hip_bfloat16* __restrict__ Wt1, __hip_bfloat16* __restrict__ Wt2,
    __hip_bfloat16* __restrict__ Wt3, __hip_bfloat16* __restrict__ Wpt,
    int K, int E, int nbO, int nbK)
{
    int bid = blockIdx.x, tid = threadIdx.x;
    if (bid < nbO) {                       // per-graph edge offsets (eb_b sorted)
        int e = bid * 256 + tid;
        if (e >= E) return;
        int b = eb_b[e];
        if (e == 0) { for (int bb = 0; bb <= b; ++bb) off[bb] = 0; }
        else { int pb = eb_b[e - 1]; for (int bb = pb + 1; bb <= b; ++bb) off[bb] = e; }
        if (e == E - 1) { for (int bb = b + 1; bb <= NN; ++bb) off[bb] = E; }
        return;
    }
    bid -= nbO;
    if (bid < nbK) {                       // per-edge K-offsets (igeb sorted)
        int k = bid * 256 + tid;
        if (k >= K) return;
        int e = igeb[k];
        if (k == 0) { for (int ee = 0; ee <= e; ++ee) eoff[ee] = 0; }
        else { int pe = igeb[k - 1]; for (int ee = pe + 1; ee <= e; ++ee) eoff[ee] = k; }
        if (k == K - 1) { for (int ee = e + 1; ee <= E; ++ee) eoff[ee] = K; }
        return;
    }
    bid -= nbK;
    // weight transpose/convert (2 output-cols per block)
    int c = bid * 2 + (tid >> 7), k = tid & 127;
    int cc = c & 127; bool hi = c >= 128;
    if (!hi) {                             // emb-top half only (att-top cancels in softmax)
        Wt1[c * 128 + k] = __float2bfloat16(W_emb[k * 128 + c]);
        if (k < WPSTR)
            Wpt[c * WPSTR + k] = __float2bfloat16(k < 68 ? W_pre[k * 128 + c] : 0.f);
    }
    Wt2[c * 128 + k] = __float2bfloat16(hi ? W_emb[(128 + k) * 128 + cc] : W_att[(128 + k) * 128 + cc]);
    Wt3[c * 128 + k] = __float2bfloat16(hi ? Wg_emb[k * 128 + cc]
                                           : (Wg_att[k * 128 + cc] + Wg_att[(128 + k) * 128 + cc]));
}

// Fused pre: e_in(68,bf16) -> MFMA1(@Wpt) -> tanh -> MFMA2(@Wt1) -> beB = bf16(exp(2*(be+b_emb)))
__global__ __launch_bounds__(256) void k_pre2(
    const float* __restrict__ nodes, const float* __restrict__ edges,
    const __hip_bfloat16* __restrict__ Wpt, const float* __restrict__ b_pre,
    const int* __restrict__ eb_b, const int* __restrict__ eb_n, const int* __restrict__ eb_nb,
    const __hip_bfloat16* __restrict__ Wt1, const float* __restrict__ b_emb,
    __hip_bfloat16* __restrict__ beB, int E)
{
    __shared__ __align__(16) __hip_bfloat16 eIn[64 * WPSTR];
    __shared__ __align__(16) __hip_bfloat16 eL[64 * MSTR];
    __shared__ int bL[64], nL[64], nbL[64];
    int tid = threadIdx.x;
    int e0 = blockIdx.x * 64;
    if (tid < 64) {
        int e = e0 + tid;
        int b = -1, n = 0, nb = 0;
        if (e < E) { b = eb_b[e]; n = eb_n[e]; nb = eb_nb[e]; }
        bL[tid] = b; nL[tid] = n; nbL[tid] = nb;
        float4 ev = make_float4(0.f, 0.f, 0.f, 0.f);
        if (b >= 0) ev = *(const float4*)&edges[(((size_t)b * VN + n) * VN + nb) * EFD];
        eIn[tid * WPSTR + 64] = __float2bfloat16(ev.x);
        eIn[tid * WPSTR + 65] = __float2bfloat16(ev.y);
        eIn[tid * WPSTR + 66] = __float2bfloat16(ev.z);
        eIn[tid * WPSTR + 67] = __float2bfloat16(ev.w);
        for (int f = 68; f < WPSTR; ++f) eIn[tid * WPSTR + f] = __float2bfloat16(0.f);
    }
    __syncthreads();
    #pragma unroll
    for (int it = 0; it < 16; ++it) {       // node features f<64
        int le = (tid >> 6) + it * 4, f = tid & 63;
        int b = bL[le];
        float v = 0.f;
        if (b >= 0)
            v = (f < 32) ? nodes[((size_t)b * VN + nL[le]) * NF + f]
                         : nodes[((size_t)b * VN + nbL[le]) * NF + (f - 32)];
        eIn[le * WPSTR + f] = __float2bfloat16(v);
    }
    __syncthreads();
    int wave = tid >> 6, lane = tid & 63, lm = lane & 15, lq = lane >> 4;
    int r0 = wave * 16;
    // MFMA1: e_emb = tanh(e_in @ W_pre + b_pre)
    {
        short8 Af[3];
        #pragma unroll
        for (int kb = 0; kb < 3; ++kb)
            Af[kb] = *(const short8*)((const short*)eIn + (r0 + lm) * WPSTR + kb * 32 + lq * 8);
        #pragma unroll
        for (int t = 0; t < 8; ++t) {
            short8 Bf[3];
            #pragma unroll
            for (int kb = 0; kb < 3; ++kb)
                Bf[kb] = *(const short8*)((const short*)Wpt +
                         (size_t)(t * 16 + lm) * WPSTR + kb * 32 + lq * 8);
            f32x4 acc = {0.f, 0.f, 0.f, 0.f};
            #pragma unroll
            for (int kb = 0; kb < 3; ++kb)
                acc = __builtin_amdgcn_mfma_f32_16x16x32_bf16(Af[kb], Bf[kb], acc, 0, 0, 0);
            int col = t * 16 + lm;
            float bp = b_pre[col];
            #pragma unroll
            for (int i = 0; i < 4; ++i)
                eL[(r0 + lq * 4 + i) * MSTR + col] = __float2bfloat16(fast_tanh(acc[i] + bp));
        }
    }
    __syncthreads();
    // MFMA2: beB = exp(2*(e_emb @ Wt1 + b_emb))
    {
        short8 Af[4];
        #pragma unroll
        for (int kb = 0; kb < 4; ++kb)
            Af[kb] = *(const short8*)((const short*)eL + (r0 + lm) * MSTR + kb * 32 + lq * 8);
        #pragma unroll
        for (int t = 0; t < 8; ++t) {
            short8 Bf[4];
            #pragma unroll
            for (int kb = 0; kb < 4; ++kb)
                Bf[kb] = *(const short8*)((const short*)Wt1 +
                         (size_t)(t * 16 + lm) * 128 + kb * 32 + lq * 8);
            f32x4 acc = {0.f, 0.f, 0.f, 0.f};
            #pragma unroll
            for (int kb = 0; kb < 4; ++kb)
                acc = __builtin_amdgcn_mfma_f32_16x16x32_bf16(Af[kb], Bf[kb], acc, 0, 0, 0);
            int col = t * 16 + lm;
            float bv = b_emb[col];
            #pragma unroll
            for (int i = 0; i < 4; ++i)
                beB[(size_t)(e0 + r0 + lq * 4 + i) * 128 + col] =
                    __float2bfloat16(__expf(2.f * (acc[i] + bv)));
        }
    }
}

// Fully-fused per-graph MP + readout. 1024 threads (16 waves), ~79 KB LDS, 2 blocks/CU.
// Key: with NW=16, each wave's GEMM column stripe (col0 = wave*16) is fixed -> B-frags hoisted to VGPRs.
__global__ __launch_bounds__(NT, 8) void k_mp(
    const __hip_bfloat16* __restrict__ beB,
    const __hip_bfloat16* __restrict__ Wt2, const __hip_bfloat16* __restrict__ Wt3,
    const float* __restrict__ bg_att, const float* __restrict__ bg_emb,
    const int* __restrict__ igeb, const int* __restrict__ ige, const int* __restrict__ ieb,
    const int* __restrict__ eoff,
    const int* __restrict__ eb_n, const float* __restrict__ node_mask,
    const float* __restrict__ W_out, const float* __restrict__ b_out,
    const int* __restrict__ off, float* __restrict__ out)
{
    __shared__ __align__(16) char pool[75264];
    __shared__ float gembL[128];
    __shared__ float nmL[VN];
    __shared__ int srcL[EMAX * DMAX];    // LOCAL source index or -1
    __shared__ int nodeL[EMAX];
    __hip_bfloat16* memL  = (__hip_bfloat16*)pool;            // [96][MSTR]
    unsigned*       MaMeL = (unsigned*)(pool + 26112);        // [96][128] lo=bf16(exp(Ma)) hi=bf16(exp(2Me))
    float*          nsF   = (float*)pool;                     // [40][128] (over memL after Mae step1)
    __hip_bfloat16* nsbL  = (__hip_bfloat16*)(pool + 26112);  // [48][MSTR]
    unsigned*       GOLp  = (unsigned*)(pool + 39168);        // [48][128] packed exp
    float*          numP  = (float*)pool;                     // [1024] (post-GO, over memL)
    float*          denP  = (float*)(pool + 4096);            // [1024]
    float*          redL  = (float*)(pool + 8192);            // [1024]

    int b = blockIdx.x;
    int s0 = off[b], s1 = off[b + 1];
    int nE = s1 - s0;
    int tid = threadIdx.x;
    int wave = tid >> 6, lane = tid & 63, lm = lane & 15, lq = lane >> 4;
    int colw = wave * 16 + lm;            // this wave's fixed GEMM output column
    int ccw = colw & 127;
    bool attHalf = colw < 128;

    // Hoist Wt2 B-fragments (fixed stripe per wave; live through the MP loop)
    short8 BW[4];
    #pragma unroll
    for (int kb = 0; kb < 4; ++kb)
        BW[kb] = *(const short8*)((const short*)Wt2 + (size_t)colw * 128 + kb * 32 + lq * 8);

    // stage: srcL = -1, node ids, node mask
    for (int idx = tid; idx < EMAX * DMAX; idx += NT) srcL[idx] = -1;
    if (tid < EMAX) nodeL[tid] = (tid < nE) ? eb_n[s0 + tid] : 0;
    if (tid < VN) nmL[tid] = node_mask[b * VN + tid];
    __syncthreads();
    // scatter this graph's K-slice into srcL (local indices)
    {
        int k0 = eoff[s0], k1 = eoff[s1];
        for (int k = k0 + tid; k < k1; k += NT)
            srcL[(igeb[k] - s0) * DMAX + ige[k]] = ieb[k] - s0;
    }

    // step 0 closed form: mem = tanh(bec) = 1 - 2/(e2be+1); pads zero
    for (int idx = tid; idx < EMAX * 128; idx += NT) {
        int le = idx >> 7, c = idx & 127;
        float v = 0.f;
        if (le < nE) {
            float e2be = __bfloat162float(beB[(size_t)(s0 + le) * 128 + c]);
            v = fmaf(-2.f, __builtin_amdgcn_rcpf(e2be + 1.f), 1.f);
        }
        memL[le * MSTR + c] = __float2bfloat16(v);
    }
    __syncthreads();

    for (int step = 0; step < 2; ++step) {
        // Mae = mem @ Wt2: 6 row-tiles on this wave's fixed col stripe (B in registers)
        #pragma unroll 2
        for (int r = 0; r < 6; ++r) {
            short8 Af[4];
            #pragma unroll
            for (int kb = 0; kb < 4; ++kb)
                Af[kb] = *(const short8*)((const short*)memL + (r * 16 + lm) * MSTR + kb * 32 + lq * 8);
            f32x4 acc = {0.f, 0.f, 0.f, 0.f};
            #pragma unroll
            for (int kb = 0; kb < 4; ++kb)
                acc = __builtin_amdgcn_mfma_f32_16x16x32_bf16(Af[kb], BW[kb], acc, 0, 0, 0);
            __hip_bfloat16* hp = (__hip_bfloat16*)MaMeL;
            if (attHalf) {
                #pragma unroll
                for (int i2 = 0; i2 < 4; ++i2)
                    hp[((r * 16 + lq * 4 + i2) * 128 + ccw) * 2] =
                        __float2bfloat16(__expf(acc[i2]));
            } else {
                #pragma unroll
                for (int i2 = 0; i2 < 4; ++i2)
                    hp[((r * 16 + lq * 4 + i2) * 128 + ccw) * 2 + 1] =
                        __float2bfloat16(__expf(2.f * acc[i2]));
            }
        }
        __syncthreads();
        if (step == 1) {       // memL dead; zero nsF (same LDS) before scatter
            for (int idx = tid; idx < VN * 128; idx += NT) nsF[idx] = 0.f;
            __syncthreads();
        }
        // msg: wave-per-edge; src indices via readlane; scalar-skip dead slots
        for (int le = wave; le < nE; le += NW) {
            int sv = srcL[le * DMAX + (lane & 7)];
            float e2b0 = __bfloat162float(beB[(size_t)(s0 + le) * 128 + lane]);
            float e2b1 = __bfloat162float(beB[(size_t)(s0 + le) * 128 + 64 + lane]);
            float sw0 = 0.f, swr0 = 0.f, sw1 = 0.f, swr1 = 0.f;
            bool anyV = false;
            #pragma unroll
            for (int d = 0; d < DMAX; ++d) {
                int ls = __builtin_amdgcn_readlane(sv, d);
                if (ls >= 0) {
                    anyV = true;
                    unsigned pk0 = MaMeL[ls * 128 + lane];
                    unsigned pk1 = MaMeL[ls * 128 + 64 + lane];
                    float w0 = __uint_as_float(pk0 << 16);
                    float m0 = __uint_as_float(pk0 & 0xFFFF0000u);
                    float w1 = __uint_as_float(pk1 << 16);
                    float m1 = __uint_as_float(pk1 & 0xFFFF0000u);
                    sw0 += w0;
                    swr0 = fmaf(w0, __builtin_amdgcn_rcpf(fmaf(e2b0, m0, 1.f)), swr0);
                    sw1 += w1;
                    swr1 = fmaf(w1, __builtin_amdgcn_rcpf(fmaf(e2b1, m1, 1.f)), swr1);
                }
            }
            float r0 = anyV ? swr0 * __builtin_amdgcn_rcpf(sw0)
                            : __builtin_amdgcn_rcpf(e2b0 + 1.f);
            float r1 = anyV ? swr1 * __builtin_amdgcn_rcpf(sw1)
                            : __builtin_amdgcn_rcpf(e2b1 + 1.f);
            float v0 = fmaf(-2.f, r0, 1.f);
            float v1 = fmaf(-2.f, r1, 1.f);
            if (step == 0) {
                memL[le * MSTR + lane] = __float2bfloat16(v0);
                memL[le * MSTR + 64 + lane] = __float2bfloat16(v1);
            } else {           // final step: scatter straight into node sums
                int v = __builtin_amdgcn_readfirstlane(nodeL[le]);
                atomicAdd(&nsF[v * 128 + lane], v0);
                atomicAdd(&nsF[v * 128 + 64 + lane], v1);
            }
        }
        __syncthreads();
    }

    // nsF -> bf16 nsbL (pads zero)
    for (int idx = tid; idx < 48 * 128; idx += NT) {
        int v = idx >> 7, k = idx & 127;
        nsbL[v * MSTR + k] = __float2bfloat16(v < VN ? nsF[idx] : 0.f);
    }
    // GO B-fragments (fixed stripe; short live range) — load while nsbL settles
    short8 BG[4];
    #pragma unroll
    for (int kb = 0; kb < 4; ++kb)
        BG[kb] = *(const short8*)((const short*)Wt3 + (size_t)colw * 128 + kb * 32 + lq * 8);
    float bvGO = attHalf ? bg_att[colw] : bg_emb[ccw];
    __syncthreads();
    // GO = nsb @ Wt3 + bias : 3 row-tiles on fixed col stripe; packs {exp(att), exp(2*emb)}
    #pragma unroll
    for (int r = 0; r < 3; ++r) {
        short8 Af[4];
        #pragma unroll
        for (int kb = 0; kb < 4; ++kb)
            Af[kb] = *(const short8*)((const short*)nsbL + (r * 16 + lm) * MSTR + kb * 32 + lq * 8);
        f32x4 acc = {0.f, 0.f, 0.f, 0.f};
        #pragma unroll
        for (int kb = 0; kb < 4; ++kb)
            acc = __builtin_amdgcn_mfma_f32_16x16x32_bf16(Af[kb], BG[kb], acc, 0, 0, 0);
        __hip_bfloat16* hp = (__hip_bfloat16*)GOLp;
        if (attHalf) {
            #pragma unroll
            for (int i2 = 0; i2 < 4; ++i2)
                hp[((r * 16 + lq * 4 + i2) * 128 + ccw) * 2] =
                    __float2bfloat16(__expf(acc[i2] + bvGO));
        } else {
            #pragma unroll
            for (int i2 = 0; i2 < 4; ++i2)
                hp[((r * 16 + lq * 4 + i2) * 128 + ccw) * 2 + 1] =
                    __float2bfloat16(__expf(2.f * (acc[i2] + bvGO)));
        }
    }
    __syncthreads();
    // node softmax: 8-way v-split; gemb = 1 - 2*Σ(w*r)/Σw
    {
        int c = tid & 127, q = tid >> 7;
        float sw = 0.f, swr = 0.f;
        for (int v = q; v < VN; v += 8) {
            if (nmL[v] == 0.f) continue;
            unsigned pk = GOLp[v * 128 + c];
            float w = __uint_as_float(pk << 16);
            float e2 = __uint_as_float(pk & 0xFFFF0000u);
            sw += w;
            swr = fmaf(w, __builtin_amdgcn_rcpf(e2 + 1.f), swr);
        }
        numP[tid] = swr;
        denP[tid] = sw;
    }
    __syncthreads();
    if (tid < 128) {
        float swr = 0.f, sw = 0.f;
        #pragma unroll
        for (int p = 0; p < 8; ++p) { swr += numP[p * 128 + tid]; sw += denP[p * 128 + tid]; }
        gembL[tid] = fmaf(-2.f, swr / sw, 1.f);
    }
    __syncthreads();
    // out = gemb @ W_out + b_out (8-way j-split)
    {
        int c = tid & 127, h = tid >> 7;
        float acc = 0.f;
        for (int j = h; j < 128; j += 8)
            acc += gembL[j] * W_out[j * OUTD + c];
        redL[tid] = acc;
    }
    __syncthreads();
    if (tid < 128) {
        float acc = b_out[tid];
        #pragma unroll
        for (int p = 0; p < 8; ++p) acc += redL[p * 128 + tid];
        out[(size_t)b * OUTD + tid] = acc;
    }
}

extern "C" void kernel_launch(void* const* d_in, const int* in_sizes, int n_in,
                              void* d_out, int out_size, void* d_ws, size_t ws_size,
                              hipStream_t stream) {
    const float* nodes    = (const float*)d_in[0];
    const float* edges    = (const float*)d_in[1];
    const float* W_pre    = (const float*)d_in[2];
    const float* b_pre    = (const float*)d_in[3];
    const float* W_att    = (const float*)d_in[4];
    const float* W_emb    = (const float*)d_in[6];
    const float* b_emb    = (const float*)d_in[7];
    const float* Wg_att   = (const float*)d_in[8];
    const float* bg_att   = (const float*)d_in[9];
    const float* Wg_emb   = (const float*)d_in[10];
    const float* bg_emb   = (const float*)d_in[11];
    const float* W_out    = (const float*)d_in[12];
    const float* b_out    = (const float*)d_in[13];
    const float* node_mask = (const float*)d_in[15];
    const int* eb_b   = (const int*)d_in[16];
    const int* eb_n   = (const int*)d_in[17];
    const int* eb_nb  = (const int*)d_in[18];
    const int* in_eb  = (const int*)d_in[19];
    const int* in_igeb = (const int*)d_in[20];
    const int* in_ige  = (const int*)d_in[21];

    int E = in_sizes[16];
    int K = in_sizes[19];
    int E64 = (E + 63) & ~63;

    __hip_bfloat16* Wt1 = (__hip_bfloat16*)d_ws;              // 128*128
    __hip_bfloat16* Wt2 = Wt1 + 128 * 128;                    // 256*128
    __hip_bfloat16* Wt3 = Wt2 + 256 * 128;                    // 256*128
    __hip_bfloat16* Wpt = Wt3 + 256 * 128;                    // 128*WPSTR
    __hip_bfloat16* beB = Wpt + 128 * WPSTR;                  // (E64+128)*128
    int* off  = (int*)(beB + (size_t)(E64 + 128) * 128);      // NN+1
    int* eoff = off + (NN + 1);                               // E+1

    int nbO = (E + 255) / 256;
    int nbK = (K + 255) / 256;

    k_setup<<<nbO + nbK + 128, 256, 0, stream>>>(in_igeb, eb_b,
                                                 W_att, W_emb, Wg_att, Wg_emb, W_pre,
                                                 off, eoff, Wt1, Wt2, Wt3, Wpt,
                                                 K, E, nbO, nbK);
    k_pre2<<<E64 / 64, 256, 0, stream>>>(nodes, edges, Wpt, b_pre,
                                         eb_b, eb_n, eb_nb, Wt1, b_emb, beB, E);
    k_mp<<<NN, NT, 0, stream>>>(beB, Wt2, Wt3, bg_att, bg_emb,
                                in_igeb, in_ige, in_eb, eoff, eb_n, node_mask,
                                W_out, b_out, off, (float*)d_out);
}

// Round 14
// 190.437 us; speedup vs baseline: 1.0208x; 1.0208x over previous
//
#include <hip/hip_runtime.h>
#include <hip/hip_bf16.h>
#include <math.h>

#define NN 512
#define VN 40
#define NF 32
#define EFD 4
#define OUTD 128
#define EMAX 96     // max directed edges per graph (<= 90 actual)
#define DMAX 8      // max in-degree
#define MSTR 136    // LDS row stride (shorts) for 128-wide MFMA A-operands
#define WPSTR 104   // row stride (shorts) for 96-wide (68-padded) operands
#define NT 1024     // k_mp threads (16 waves)
#define NW 16

typedef __attribute__((ext_vector_type(8))) short short8;
typedef __attribute__((ext_vector_type(4))) float f32x4;

// tanh(x) = 1 - 2/(exp(2x)+1)
__device__ __forceinline__ float fast_tanh(float x) {
    return fmaf(-2.0f, __builtin_amdgcn_rcpf(__expf(2.0f * x) + 1.0f), 1.0f);
}

// Setup: [0,nbO): off boundaries | [nbO,+nbK): eoff boundaries | [+128): weight conv
__global__ __launch_bounds__(256) void k_setup(
    const int* __restrict__ igeb, const int* __restrict__ eb_b,
    const float* __restrict__ W_att, const float* __restrict__ W_emb,
    const float* __restrict__ Wg_att, const float* __restrict__ Wg_emb,
    const float* __restrict__ W_pre,
    int* __restrict__ off, int* __restrict__ eoff,
    __hip_bfloat16* __restrict__ Wt1, __hip_bfloat16* __restrict__ Wt2,
    __hip_bfloat16* __restrict__ Wt3, __hip_bfloat16* __restrict__ Wpt,
    int K, int E, int nbO, int nbK)
{
    int bid = blockIdx.x, tid = threadIdx.x;
    if (bid < nbO) {                       // per-graph edge offsets (eb_b sorted)
        int e = bid * 256 + tid;
        if (e >= E) return;
        int b = eb_b[e];
        if (e == 0) { for (int bb = 0; bb <= b; ++bb) off[bb] = 0; }
        else { int pb = eb_b[e - 1]; for (int bb = pb + 1; bb <= b; ++bb) off[bb] = e; }
        if (e == E - 1) { for (int bb = b + 1; bb <= NN; ++bb) off[bb] = E; }
        return;
    }
    bid -= nbO;
    if (bid < nbK) {                       // per-edge K-offsets (igeb sorted)
        int k = bid * 256 + tid;
        if (k >= K) return;
        int e = igeb[k];
        if (k == 0) { for (int ee = 0; ee <= e; ++ee) eoff[ee] = 0; }
        else { int pe = igeb[k - 1]; for (int ee = pe + 1; ee <= e; ++ee) eoff[ee] = k; }
        if (k == K - 1) { for (int ee = e + 1; ee <= E; ++ee) eoff[ee] = K; }
        return;
    }
    bid -= nbK;
    // weight transpose/convert (2 output-cols per block)
    int c = bid * 2 + (tid >> 7), k = tid & 127;
    int cc = c & 127; bool hi = c >= 128;
    if (!hi) {                             // emb-top half only (att-top cancels in softmax)
        Wt1[c * 128 + k] = __float2bfloat16(W_emb[k * 128 + c]);
        if (k < WPSTR)
            Wpt[c * WPSTR + k] = __float2bfloat16(k < 68 ? W_pre[k * 128 + c] : 0.f);
    }
    Wt2[c * 128 + k] = __float2bfloat16(hi ? W_emb[(128 + k) * 128 + cc] : W_att[(128 + k) * 128 + cc]);
    Wt3[c * 128 + k] = __float2bfloat16(hi ? Wg_emb[k * 128 + cc]
                                           : (Wg_att[k * 128 + cc] + Wg_att[(128 + k) * 128 + cc]));
}

// Fused pre: e_in(68,bf16) -> MFMA1(@Wpt) -> tanh -> MFMA2(@Wt1) -> beB = bf16(exp(2*(be+b_emb)))
__global__ __launch_bounds__(256) void k_pre2(
    const float* __restrict__ nodes, const float* __restrict__ edges,
    const __hip_bfloat16* __restrict__ Wpt, const float* __restrict__ b_pre,
    const int* __restrict__ eb_b, const int* __restrict__ eb_n, const int* __restrict__ eb_nb,
    const __hip_bfloat16* __restrict__ Wt1, const float* __restrict__ b_emb,
    __hip_bfloat16* __restrict__ beB, int E)
{
    __shared__ __align__(16) __hip_bfloat16 eIn[64 * WPSTR];
    __shared__ __align__(16) __hip_bfloat16 eL[64 * MSTR];
    __shared__ int bL[64], nL[64], nbL[64];
    int tid = threadIdx.x;
    int e0 = blockIdx.x * 64;
    if (tid < 64) {
        int e = e0 + tid;
        int b = -1, n = 0, nb = 0;
        if (e < E) { b = eb_b[e]; n = eb_n[e]; nb = eb_nb[e]; }
        bL[tid] = b; nL[tid] = n; nbL[tid] = nb;
        float4 ev = make_float4(0.f, 0.f, 0.f, 0.f);
        if (b >= 0) ev = *(const float4*)&edges[(((size_t)b * VN + n) * VN + nb) * EFD];
        eIn[tid * WPSTR + 64] = __float2bfloat16(ev.x);
        eIn[tid * WPSTR + 65] = __float2bfloat16(ev.y);
        eIn[tid * WPSTR + 66] = __float2bfloat16(ev.z);
        eIn[tid * WPSTR + 67] = __float2bfloat16(ev.w);
        for (int f = 68; f < WPSTR; ++f) eIn[tid * WPSTR + f] = __float2bfloat16(0.f);
    }
    __syncthreads();
    // node features via float4 slot-gather: 64 edges x 16 slots (8 for n-half, 8 for nb-half)
    #pragma unroll
    for (int it = 0; it < 4; ++it) {
        int slot = tid + it * 256;
        int le = slot >> 4, seg = slot & 15;
        int b = bL[le];
        float4 v = make_float4(0.f, 0.f, 0.f, 0.f);
        if (b >= 0) {
            int node = (seg < 8) ? nL[le] : nbL[le];
            v = *(const float4*)&nodes[((size_t)b * VN + node) * NF + (seg & 7) * 4];
        }
        __hip_bfloat16* dst = &eIn[le * WPSTR + ((seg < 8) ? 0 : 32) + (seg & 7) * 4];
        dst[0] = __float2bfloat16(v.x);
        dst[1] = __float2bfloat16(v.y);
        dst[2] = __float2bfloat16(v.z);
        dst[3] = __float2bfloat16(v.w);
    }
    __syncthreads();
    int wave = tid >> 6, lane = tid & 63, lm = lane & 15, lq = lane >> 4;
    int r0 = wave * 16;
    // MFMA1: e_emb = tanh(e_in @ W_pre + b_pre)
    {
        short8 Af[3];
        #pragma unroll
        for (int kb = 0; kb < 3; ++kb)
            Af[kb] = *(const short8*)((const short*)eIn + (r0 + lm) * WPSTR + kb * 32 + lq * 8);
        #pragma unroll
        for (int t = 0; t < 8; ++t) {
            short8 Bf[3];
            #pragma unroll
            for (int kb = 0; kb < 3; ++kb)
                Bf[kb] = *(const short8*)((const short*)Wpt +
                         (size_t)(t * 16 + lm) * WPSTR + kb * 32 + lq * 8);
            f32x4 acc = {0.f, 0.f, 0.f, 0.f};
            #pragma unroll
            for (int kb = 0; kb < 3; ++kb)
                acc = __builtin_amdgcn_mfma_f32_16x16x32_bf16(Af[kb], Bf[kb], acc, 0, 0, 0);
            int col = t * 16 + lm;
            float bp = b_pre[col];
            #pragma unroll
            for (int i = 0; i < 4; ++i)
                eL[(r0 + lq * 4 + i) * MSTR + col] = __float2bfloat16(fast_tanh(acc[i] + bp));
        }
    }
    __syncthreads();
    // MFMA2: beB = exp(2*(e_emb @ Wt1 + b_emb))
    {
        short8 Af[4];
        #pragma unroll
        for (int kb = 0; kb < 4; ++kb)
            Af[kb] = *(const short8*)((const short*)eL + (r0 + lm) * MSTR + kb * 32 + lq * 8);
        #pragma unroll
        for (int t = 0; t < 8; ++t) {
            short8 Bf[4];
            #pragma unroll
            for (int kb = 0; kb < 4; ++kb)
                Bf[kb] = *(const short8*)((const short*)Wt1 +
                         (size_t)(t * 16 + lm) * 128 + kb * 32 + lq * 8);
            f32x4 acc = {0.f, 0.f, 0.f, 0.f};
            #pragma unroll
            for (int kb = 0; kb < 4; ++kb)
                acc = __builtin_amdgcn_mfma_f32_16x16x32_bf16(Af[kb], Bf[kb], acc, 0, 0, 0);
            int col = t * 16 + lm;
            float bv = b_emb[col];
            #pragma unroll
            for (int i = 0; i < 4; ++i)
                beB[(size_t)(e0 + r0 + lq * 4 + i) * 128 + col] =
                    __float2bfloat16(__expf(2.f * (acc[i] + bv)));
        }
    }
}

// Fully-fused per-graph MP + readout. 1024 threads (16 waves), ~79 KB LDS, 2 blocks/CU.
__global__ __launch_bounds__(NT, 8) void k_mp(
    const __hip_bfloat16* __restrict__ beB,
    const __hip_bfloat16* __restrict__ Wt2, const __hip_bfloat16* __restrict__ Wt3,
    const float* __restrict__ bg_att, const float* __restrict__ bg_emb,
    const int* __restrict__ igeb, const int* __restrict__ ige, const int* __restrict__ ieb,
    const int* __restrict__ eoff,
    const int* __restrict__ eb_n, const float* __restrict__ node_mask,
    const float* __restrict__ W_out, const float* __restrict__ b_out,
    const int* __restrict__ off, float* __restrict__ out)
{
    __shared__ __align__(16) char pool[75264];
    __shared__ float gembL[128];
    __shared__ float nmL[VN];
    __shared__ int srcL[EMAX * DMAX];    // LOCAL source index or -1
    __shared__ int nodeL[EMAX];
    __hip_bfloat16* memL  = (__hip_bfloat16*)pool;            // [96][MSTR]
    unsigned*       MaMeL = (unsigned*)(pool + 26112);        // [96][128] lo=bf16(exp(Ma)) hi=bf16(exp(2Me))
    float*          nsF   = (float*)pool;                     // [40][128] (over memL after Mae step1)
    __hip_bfloat16* nsbL  = (__hip_bfloat16*)(pool + 26112);  // [48][MSTR]
    unsigned*       GOLp  = (unsigned*)(pool + 39168);        // [48][128] packed exp
    float*          numP  = (float*)pool;                     // [1024] (post-GO, over memL)
    float*          denP  = (float*)(pool + 4096);            // [1024]
    float*          redL  = (float*)(pool + 8192);            // [1024]

    int b = blockIdx.x;
    int s0 = off[b], s1 = off[b + 1];
    int nE = s1 - s0;
    int tid = threadIdx.x;
    int wave = tid >> 6, lane = tid & 63, lm = lane & 15, lq = lane >> 4;

    // stage: srcL = -1, node ids, node mask
    for (int idx = tid; idx < EMAX * DMAX; idx += NT) srcL[idx] = -1;
    if (tid < EMAX) nodeL[tid] = (tid < nE) ? eb_n[s0 + tid] : 0;
    if (tid < VN) nmL[tid] = node_mask[b * VN + tid];
    __syncthreads();
    // scatter this graph's K-slice into srcL (local indices)
    {
        int k0 = eoff[s0], k1 = eoff[s1];
        for (int k = k0 + tid; k < k1; k += NT)
            srcL[(igeb[k] - s0) * DMAX + ige[k]] = ieb[k] - s0;
    }

    // step 0 closed form: mem = tanh(bec) = 1 - 2/(e2be+1); pads zero
    for (int idx = tid; idx < EMAX * 128; idx += NT) {
        int le = idx >> 7, c = idx & 127;
        float v = 0.f;
        if (le < nE) {
            float e2be = __bfloat162float(beB[(size_t)(s0 + le) * 128 + c]);
            v = fmaf(-2.f, __builtin_amdgcn_rcpf(e2be + 1.f), 1.f);
        }
        memL[le * MSTR + c] = __float2bfloat16(v);
    }
    __syncthreads();

    for (int step = 0; step < 2; ++step) {
        // Mae = mem @ Wt2 (96 tiles over 16 waves); epilogue packs {exp(Ma), exp(2*Me)}
        for (int t = wave; t < 96; t += NW) {
            int r = t >> 4;
            int col0 = (t & 15) * 16;
            short8 Af[4], Bg[4];
            #pragma unroll
            for (int kb = 0; kb < 4; ++kb) {
                Af[kb] = *(const short8*)((const short*)memL + (r * 16 + lm) * MSTR + kb * 32 + lq * 8);
                Bg[kb] = *(const short8*)((const short*)Wt2 + (size_t)(col0 + lm) * 128 + kb * 32 + lq * 8);
            }
            f32x4 acc = {0.f, 0.f, 0.f, 0.f};
            #pragma unroll
            for (int kb = 0; kb < 4; ++kb)
                acc = __builtin_amdgcn_mfma_f32_16x16x32_bf16(Af[kb], Bg[kb], acc, 0, 0, 0);
            int col = col0 + lm;
            int cc = col & 127;
            __hip_bfloat16* hp = (__hip_bfloat16*)MaMeL;
            if (col < 128) {
                #pragma unroll
                for (int i2 = 0; i2 < 4; ++i2)
                    hp[((r * 16 + lq * 4 + i2) * 128 + cc) * 2] =
                        __float2bfloat16(__expf(acc[i2]));
            } else {
                #pragma unroll
                for (int i2 = 0; i2 < 4; ++i2)
                    hp[((r * 16 + lq * 4 + i2) * 128 + cc) * 2 + 1] =
                        __float2bfloat16(__expf(2.f * acc[i2]));
            }
        }
        __syncthreads();
        if (step == 1) {       // memL dead; zero nsF (same LDS) before scatter
            for (int idx = tid; idx < VN * 128; idx += NT) nsF[idx] = 0.f;
            __syncthreads();
        }
        // msg: wave-per-edge; FIXED 6 iterations (EMAX/NW), predicated -> unrollable,
        // loads from independent edges batch together instead of serializing.
        #pragma unroll
        for (int i = 0; i < 6; ++i) {
            int le = wave + i * NW;
            bool act = le < nE;
            int sv = srcL[le * DMAX + (lane & 7)];
            float e2b0 = __bfloat162float(beB[(size_t)(s0 + le) * 128 + lane]);
            float e2b1 = __bfloat162float(beB[(size_t)(s0 + le) * 128 + 64 + lane]);
            float sw0 = 0.f, swr0 = 0.f, sw1 = 0.f, swr1 = 0.f;
            bool anyV = false;
            #pragma unroll
            for (int d = 0; d < DMAX; ++d) {
                int ls = __builtin_amdgcn_readlane(sv, d);
                if (ls >= 0) {
                    anyV = true;
                    unsigned pk0 = MaMeL[ls * 128 + lane];
                    unsigned pk1 = MaMeL[ls * 128 + 64 + lane];
                    float w0 = __uint_as_float(pk0 << 16);
                    float m0 = __uint_as_float(pk0 & 0xFFFF0000u);
                    float w1 = __uint_as_float(pk1 << 16);
                    float m1 = __uint_as_float(pk1 & 0xFFFF0000u);
                    sw0 += w0;
                    swr0 = fmaf(w0, __builtin_amdgcn_rcpf(fmaf(e2b0, m0, 1.f)), swr0);
                    sw1 += w1;
                    swr1 = fmaf(w1, __builtin_amdgcn_rcpf(fmaf(e2b1, m1, 1.f)), swr1);
                }
            }
            float r0 = anyV ? swr0 * __builtin_amdgcn_rcpf(sw0)
                            : __builtin_amdgcn_rcpf(e2b0 + 1.f);
            float r1 = anyV ? swr1 * __builtin_amdgcn_rcpf(sw1)
                            : __builtin_amdgcn_rcpf(e2b1 + 1.f);
            float v0 = fmaf(-2.f, r0, 1.f);
            float v1 = fmaf(-2.f, r1, 1.f);
            if (act) {
                if (step == 0) {
                    memL[le * MSTR + lane] = __float2bfloat16(v0);
                    memL[le * MSTR + 64 + lane] = __float2bfloat16(v1);
                } else {       // final step: scatter straight into node sums
                    int v = __builtin_amdgcn_readfirstlane(nodeL[le]);
                    atomicAdd(&nsF[v * 128 + lane], v0);
                    atomicAdd(&nsF[v * 128 + 64 + lane], v1);
                }
            }
        }
        __syncthreads();
    }

    // nsF -> bf16 nsbL (pads zero)
    for (int idx = tid; idx < 48 * 128; idx += NT) {
        int v = idx >> 7, k = idx & 127;
        nsbL[v * MSTR + k] = __float2bfloat16(v < VN ? nsF[idx] : 0.f);
    }
    __syncthreads();
    // GO = nsb @ Wt3 + bias : 48 tiles; epilogue packs {exp(att), exp(2*emb)}
    for (int t = wave; t < 48; t += NW) {
        int r = t >> 4;
        int col0 = (t & 15) * 16;
        short8 Af[4], Bg[4];
        #pragma unroll
        for (int kb = 0; kb < 4; ++kb) {
            Af[kb] = *(const short8*)((const short*)nsbL + (r * 16 + lm) * MSTR + kb * 32 + lq * 8);
            Bg[kb] = *(const short8*)((const short*)Wt3 + (size_t)(col0 + lm) * 128 + kb * 32 + lq * 8);
        }
        f32x4 acc = {0.f, 0.f, 0.f, 0.f};
        #pragma unroll
        for (int kb = 0; kb < 4; ++kb)
            acc = __builtin_amdgcn_mfma_f32_16x16x32_bf16(Af[kb], Bg[kb], acc, 0, 0, 0);
        int col = col0 + lm;
        int cc = col & 127;
        float bv = (col < 128) ? bg_att[col] : bg_emb[cc];
        __hip_bfloat16* hp = (__hip_bfloat16*)GOLp;
        if (col < 128) {
            #pragma unroll
            for (int i2 = 0; i2 < 4; ++i2)
                hp[((r * 16 + lq * 4 + i2) * 128 + cc) * 2] =
                    __float2bfloat16(__expf(acc[i2] + bv));
        } else {
            #pragma unroll
            for (int i2 = 0; i2 < 4; ++i2)
                hp[((r * 16 + lq * 4 + i2) * 128 + cc) * 2 + 1] =
                    __float2bfloat16(__expf(2.f * (acc[i2] + bv)));
        }
    }
    __syncthreads();
    // node softmax: 8-way v-split; gemb = 1 - 2*Σ(w*r)/Σw
    {
        int c = tid & 127, q = tid >> 7;
        float sw = 0.f, swr = 0.f;
        for (int v = q; v < VN; v += 8) {
            if (nmL[v] == 0.f) continue;
            unsigned pk = GOLp[v * 128 + c];
            float w = __uint_as_float(pk << 16);
            float e2 = __uint_as_float(pk & 0xFFFF0000u);
            sw += w;
            swr = fmaf(w, __builtin_amdgcn_rcpf(e2 + 1.f), swr);
        }
        numP[tid] = swr;
        denP[tid] = sw;
    }
    __syncthreads();
    if (tid < 128) {
        float swr = 0.f, sw = 0.f;
        #pragma unroll
        for (int p = 0; p < 8; ++p) { swr += numP[p * 128 + tid]; sw += denP[p * 128 + tid]; }
        gembL[tid] = fmaf(-2.f, swr / sw, 1.f);
    }
    __syncthreads();
    // out = gemb @ W_out + b_out (8-way j-split)
    {
        int c = tid & 127, h = tid >> 7;
        float acc = 0.f;
        for (int j = h; j < 128; j += 8)
            acc += gembL[j] * W_out[j * OUTD + c];
        redL[tid] = acc;
    }
    __syncthreads();
    if (tid < 128) {
        float acc = b_out[tid];
        #pragma unroll
        for (int p = 0; p < 8; ++p) acc += redL[p * 128 + tid];
        out[(size_t)b * OUTD + tid] = acc;
    }
}

extern "C" void kernel_launch(void* const* d_in, const int* in_sizes, int n_in,
                              void* d_out, int out_size, void* d_ws, size_t ws_size,
                              hipStream_t stream) {
    const float* nodes    = (const float*)d_in[0];
    const float* edges    = (const float*)d_in[1];
    const float* W_pre    = (const float*)d_in[2];
    const float* b_pre    = (const float*)d_in[3];
    const float* W_att    = (const float*)d_in[4];
    const float* W_emb    = (const float*)d_in[6];
    const float* b_emb    = (const float*)d_in[7];
    const float* Wg_att   = (const float*)d_in[8];
    const float* bg_att   = (const float*)d_in[9];
    const float* Wg_emb   = (const float*)d_in[10];
    const float* bg_emb   = (const float*)d_in[11];
    const float* W_out    = (const float*)d_in[12];
    const float* b_out    = (const float*)d_in[13];
    const float* node_mask = (const float*)d_in[15];
    const int* eb_b   = (const int*)d_in[16];
    const int* eb_n   = (const int*)d_in[17];
    const int* eb_nb  = (const int*)d_in[18];
    const int* in_eb  = (const int*)d_in[19];
    const int* in_igeb = (const int*)d_in[20];
    const int* in_ige  = (const int*)d_in[21];

    int E = in_sizes[16];
    int K = in_sizes[19];
    int E64 = (E + 63) & ~63;

    __hip_bfloat16* Wt1 = (__hip_bfloat16*)d_ws;              // 128*128
    __hip_bfloat16* Wt2 = Wt1 + 128 * 128;                    // 256*128
    __hip_bfloat16* Wt3 = Wt2 + 256 * 128;                    // 256*128
    __hip_bfloat16* Wpt = Wt3 + 256 * 128;                    // 128*WPSTR
    __hip_bfloat16* beB = Wpt + 128 * WPSTR;                  // (E64+128)*128
    int* off  = (int*)(beB + (size_t)(E64 + 128) * 128);      // NN+1
    int* eoff = off + (NN + 1);                               // E+1

    int nbO = (E + 255) / 256;
    int nbK = (K + 255) / 256;

    k_setup<<<nbO + nbK + 128, 256, 0, stream>>>(in_igeb, eb_b,
                                                 W_att, W_emb, Wg_att, Wg_emb, W_pre,
                                                 off, eoff, Wt1, Wt2, Wt3, Wpt,
                                                 K, E, nbO, nbK);
    k_pre2<<<E64 / 64, 256, 0, stream>>>(nodes, edges, Wpt, b_pre,
                                         eb_b, eb_n, eb_nb, Wt1, b_emb, beB, E);
    k_mp<<<NN, NT, 0, stream>>>(beB, Wt2, Wt3, bg_att, bg_emb,
                                in_igeb, in_ige, in_eb, eoff, eb_n, node_mask,
                                W_out, b_out, off, (float*)d_out);
}

// Round 15
// 189.016 us; speedup vs baseline: 1.0285x; 1.0075x over previous
//
#include <hip/hip_runtime.h>
#include <hip/hip_bf16.h>
#include <math.h>

#define NN 512
#define VN 40
#define NF 32
#define EFD 4
#define OUTD 128
#define EMAX 96     // max directed edges per graph (<= 90 actual)
#define DMAX 8      // max in-degree
#define MSTR 136    // LDS row stride (shorts) for 128-wide MFMA A-operands
#define WPSTR 104   // row stride (shorts) for 96-wide (68-padded) operands
#define NT 1024     // k_mp threads (16 waves)
#define NW 16

typedef __attribute__((ext_vector_type(8))) short short8;
typedef __attribute__((ext_vector_type(4))) float f32x4;

// tanh(x) = 1 - 2/(exp(2x)+1)
__device__ __forceinline__ float fast_tanh(float x) {
    return fmaf(-2.0f, __builtin_amdgcn_rcpf(__expf(2.0f * x) + 1.0f), 1.0f);
}

// Setup: [0,nbO): off boundaries | [nbO,+nbK): eoff boundaries | [+128): weight conv
__global__ __launch_bounds__(256) void k_setup(
    const int* __restrict__ igeb, const int* __restrict__ eb_b,
    const float* __restrict__ W_att, const float* __restrict__ W_emb,
    const float* __restrict__ Wg_att, const float* __restrict__ Wg_emb,
    const float* __restrict__ W_pre,
    int* __restrict__ off, int* __restrict__ eoff,
    __hip_bfloat16* __restrict__ Wt1, __hip_bfloat16* __restrict__ Wt2,
    __hip_bfloat16* __restrict__ Wt3, __hip_bfloat16* __restrict__ Wpt,
    int K, int E, int nbO, int nbK)
{
    int bid = blockIdx.x, tid = threadIdx.x;
    if (bid < nbO) {                       // per-graph edge offsets (eb_b sorted)
        int e = bid * 256 + tid;
        if (e >= E) return;
        int b = eb_b[e];
        if (e == 0) { for (int bb = 0; bb <= b; ++bb) off[bb] = 0; }
        else { int pb = eb_b[e - 1]; for (int bb = pb + 1; bb <= b; ++bb) off[bb] = e; }
        if (e == E - 1) { for (int bb = b + 1; bb <= NN; ++bb) off[bb] = E; }
        return;
    }
    bid -= nbO;
    if (bid < nbK) {                       // per-edge K-offsets (igeb sorted)
        int k = bid * 256 + tid;
        if (k >= K) return;
        int e = igeb[k];
        if (k == 0) { for (int ee = 0; ee <= e; ++ee) eoff[ee] = 0; }
        else { int pe = igeb[k - 1]; for (int ee = pe + 1; ee <= e; ++ee) eoff[ee] = k; }
        if (k == K - 1) { for (int ee = e + 1; ee <= E; ++ee) eoff[ee] = K; }
        return;
    }
    bid -= nbK;
    // weight transpose/convert (2 output-cols per block)
    int c = bid * 2 + (tid >> 7), k = tid & 127;
    int cc = c & 127; bool hi = c >= 128;
    if (!hi) {                             // emb-top half only (att-top cancels in softmax)
        Wt1[c * 128 + k] = __float2bfloat16(W_emb[k * 128 + c]);
        if (k < WPSTR)
            Wpt[c * WPSTR + k] = __float2bfloat16(k < 68 ? W_pre[k * 128 + c] : 0.f);
    }
    Wt2[c * 128 + k] = __float2bfloat16(hi ? W_emb[(128 + k) * 128 + cc] : W_att[(128 + k) * 128 + cc]);
    Wt3[c * 128 + k] = __float2bfloat16(hi ? Wg_emb[k * 128 + cc]
                                           : (Wg_att[k * 128 + cc] + Wg_att[(128 + k) * 128 + cc]));
}

// Fused pre: e_in(68,bf16) -> MFMA1(@Wpt) -> tanh -> MFMA2(@Wt1) -> beB = bf16(exp(2*(be+b_emb)))
__global__ __launch_bounds__(256) void k_pre2(
    const float* __restrict__ nodes, const float* __restrict__ edges,
    const __hip_bfloat16* __restrict__ Wpt, const float* __restrict__ b_pre,
    const int* __restrict__ eb_b, const int* __restrict__ eb_n, const int* __restrict__ eb_nb,
    const __hip_bfloat16* __restrict__ Wt1, const float* __restrict__ b_emb,
    __hip_bfloat16* __restrict__ beB, int E)
{
    __shared__ __align__(16) __hip_bfloat16 eIn[64 * WPSTR];
    __shared__ __align__(16) __hip_bfloat16 eL[64 * MSTR];
    __shared__ int bL[64], nL[64], nbL[64];
    int tid = threadIdx.x;
    int e0 = blockIdx.x * 64;
    if (tid < 64) {
        int e = e0 + tid;
        int b = -1, n = 0, nb = 0;
        if (e < E) { b = eb_b[e]; n = eb_n[e]; nb = eb_nb[e]; }
        bL[tid] = b; nL[tid] = n; nbL[tid] = nb;
        float4 ev = make_float4(0.f, 0.f, 0.f, 0.f);
        if (b >= 0) ev = *(const float4*)&edges[(((size_t)b * VN + n) * VN + nb) * EFD];
        eIn[tid * WPSTR + 64] = __float2bfloat16(ev.x);
        eIn[tid * WPSTR + 65] = __float2bfloat16(ev.y);
        eIn[tid * WPSTR + 66] = __float2bfloat16(ev.z);
        eIn[tid * WPSTR + 67] = __float2bfloat16(ev.w);
        for (int f = 68; f < WPSTR; ++f) eIn[tid * WPSTR + f] = __float2bfloat16(0.f);
    }
    __syncthreads();
    // node features via float4 slot-gather: 64 edges x 16 slots (8 for n-half, 8 for nb-half)
    #pragma unroll
    for (int it = 0; it < 4; ++it) {
        int slot = tid + it * 256;
        int le = slot >> 4, seg = slot & 15;
        int b = bL[le];
        float4 v = make_float4(0.f, 0.f, 0.f, 0.f);
        if (b >= 0) {
            int node = (seg < 8) ? nL[le] : nbL[le];
            v = *(const float4*)&nodes[((size_t)b * VN + node) * NF + (seg & 7) * 4];
        }
        __hip_bfloat16* dst = &eIn[le * WPSTR + ((seg < 8) ? 0 : 32) + (seg & 7) * 4];
        dst[0] = __float2bfloat16(v.x);
        dst[1] = __float2bfloat16(v.y);
        dst[2] = __float2bfloat16(v.z);
        dst[3] = __float2bfloat16(v.w);
    }
    __syncthreads();
    int wave = tid >> 6, lane = tid & 63, lm = lane & 15, lq = lane >> 4;
    int r0 = wave * 16;
    // MFMA1: e_emb = tanh(e_in @ W_pre + b_pre)
    {
        short8 Af[3];
        #pragma unroll
        for (int kb = 0; kb < 3; ++kb)
            Af[kb] = *(const short8*)((const short*)eIn + (r0 + lm) * WPSTR + kb * 32 + lq * 8);
        #pragma unroll
        for (int t = 0; t < 8; ++t) {
            short8 Bf[3];
            #pragma unroll
            for (int kb = 0; kb < 3; ++kb)
                Bf[kb] = *(const short8*)((const short*)Wpt +
                         (size_t)(t * 16 + lm) * WPSTR + kb * 32 + lq * 8);
            f32x4 acc = {0.f, 0.f, 0.f, 0.f};
            #pragma unroll
            for (int kb = 0; kb < 3; ++kb)
                acc = __builtin_amdgcn_mfma_f32_16x16x32_bf16(Af[kb], Bf[kb], acc, 0, 0, 0);
            int col = t * 16 + lm;
            float bp = b_pre[col];
            #pragma unroll
            for (int i = 0; i < 4; ++i)
                eL[(r0 + lq * 4 + i) * MSTR + col] = __float2bfloat16(fast_tanh(acc[i] + bp));
        }
    }
    __syncthreads();
    // MFMA2: beB = exp(2*(e_emb @ Wt1 + b_emb))
    {
        short8 Af[4];
        #pragma unroll
        for (int kb = 0; kb < 4; ++kb)
            Af[kb] = *(const short8*)((const short*)eL + (r0 + lm) * MSTR + kb * 32 + lq * 8);
        #pragma unroll
        for (int t = 0; t < 8; ++t) {
            short8 Bf[4];
            #pragma unroll
            for (int kb = 0; kb < 4; ++kb)
                Bf[kb] = *(const short8*)((const short*)Wt1 +
                         (size_t)(t * 16 + lm) * 128 + kb * 32 + lq * 8);
            f32x4 acc = {0.f, 0.f, 0.f, 0.f};
            #pragma unroll
            for (int kb = 0; kb < 4; ++kb)
                acc = __builtin_amdgcn_mfma_f32_16x16x32_bf16(Af[kb], Bf[kb], acc, 0, 0, 0);
            int col = t * 16 + lm;
            float bv = b_emb[col];
            #pragma unroll
            for (int i = 0; i < 4; ++i)
                beB[(size_t)(e0 + r0 + lq * 4 + i) * 128 + col] =
                    __float2bfloat16(__expf(2.f * (acc[i] + bv)));
        }
    }
}

// Fully-fused per-graph MP + readout. 1024 threads (16 waves), ~79 KB LDS, 2 blocks/CU.
__global__ __launch_bounds__(NT, 8) void k_mp(
    const __hip_bfloat16* __restrict__ beB,
    const __hip_bfloat16* __restrict__ Wt2, const __hip_bfloat16* __restrict__ Wt3,
    const float* __restrict__ bg_att, const float* __restrict__ bg_emb,
    const int* __restrict__ igeb, const int* __restrict__ ige, const int* __restrict__ ieb,
    const int* __restrict__ eoff,
    const int* __restrict__ eb_n, const float* __restrict__ node_mask,
    const float* __restrict__ W_out, const float* __restrict__ b_out,
    const int* __restrict__ off, float* __restrict__ out)
{
    __shared__ __align__(16) char pool[75264];
    __shared__ float gembL[128];
    __shared__ float nmL[VN];
    __shared__ int srcL[EMAX * DMAX];    // LOCAL source index or -1
    __shared__ int nodeL[EMAX];
    __hip_bfloat16* memL  = (__hip_bfloat16*)pool;            // [96][MSTR]
    unsigned*       MaMeL = (unsigned*)(pool + 26112);        // [96][128] lo=bf16(exp(Ma)) hi=bf16(exp(2Me))
    float*          nsF   = (float*)pool;                     // [40][128] (over memL after Mae step1)
    __hip_bfloat16* nsbL  = (__hip_bfloat16*)(pool + 26112);  // [48][MSTR]
    unsigned*       GOLp  = (unsigned*)(pool + 39168);        // [48][128] packed exp
    float*          numP  = (float*)pool;                     // [1024] (post-GO, over memL)
    float*          denP  = (float*)(pool + 4096);            // [1024]
    float*          redL  = (float*)(pool + 8192);            // [1024]

    int b = blockIdx.x;
    int s0 = off[b], s1 = off[b + 1];
    int nE = s1 - s0;
    int tid = threadIdx.x;
    int wave = tid >> 6, lane = tid & 63, lm = lane & 15, lq = lane >> 4;

    // stage: srcL = -1, node ids, node mask
    for (int idx = tid; idx < EMAX * DMAX; idx += NT) srcL[idx] = -1;
    if (tid < EMAX) nodeL[tid] = (tid < nE) ? eb_n[s0 + tid] : 0;
    if (tid < VN) nmL[tid] = node_mask[b * VN + tid];
    __syncthreads();
    // scatter this graph's K-slice into srcL (local indices)
    {
        int k0 = eoff[s0], k1 = eoff[s1];
        for (int k = k0 + tid; k < k1; k += NT)
            srcL[(igeb[k] - s0) * DMAX + ige[k]] = ieb[k] - s0;
    }

    // step 0 closed form: mem = tanh(bec) = 1 - 2/(e2be+1); pads zero
    for (int idx = tid; idx < EMAX * 128; idx += NT) {
        int le = idx >> 7, c = idx & 127;
        float v = 0.f;
        if (le < nE) {
            float e2be = __bfloat162float(beB[(size_t)(s0 + le) * 128 + c]);
            v = fmaf(-2.f, __builtin_amdgcn_rcpf(e2be + 1.f), 1.f);
        }
        memL[le * MSTR + c] = __float2bfloat16(v);
    }
    __syncthreads();

    for (int step = 0; step < 2; ++step) {
        // Mae = mem @ Wt2 (96 tiles over 16 waves); epilogue packs {exp(Ma), exp(2*Me)}
        for (int t = wave; t < 96; t += NW) {
            int r = t >> 4;
            int col0 = (t & 15) * 16;
            short8 Af[4], Bg[4];
            #pragma unroll
            for (int kb = 0; kb < 4; ++kb) {
                Af[kb] = *(const short8*)((const short*)memL + (r * 16 + lm) * MSTR + kb * 32 + lq * 8);
                Bg[kb] = *(const short8*)((const short*)Wt2 + (size_t)(col0 + lm) * 128 + kb * 32 + lq * 8);
            }
            f32x4 acc = {0.f, 0.f, 0.f, 0.f};
            #pragma unroll
            for (int kb = 0; kb < 4; ++kb)
                acc = __builtin_amdgcn_mfma_f32_16x16x32_bf16(Af[kb], Bg[kb], acc, 0, 0, 0);
            int col = col0 + lm;
            int cc = col & 127;
            __hip_bfloat16* hp = (__hip_bfloat16*)MaMeL;
            if (col < 128) {
                #pragma unroll
                for (int i2 = 0; i2 < 4; ++i2)
                    hp[((r * 16 + lq * 4 + i2) * 128 + cc) * 2] =
                        __float2bfloat16(__expf(acc[i2]));
            } else {
                #pragma unroll
                for (int i2 = 0; i2 < 4; ++i2)
                    hp[((r * 16 + lq * 4 + i2) * 128 + cc) * 2 + 1] =
                        __float2bfloat16(__expf(2.f * acc[i2]));
            }
        }
        __syncthreads();
        if (step == 1) {       // memL dead; zero nsF (same LDS) before scatter
            for (int idx = tid; idx < VN * 128; idx += NT) nsF[idx] = 0.f;
            __syncthreads();
        }
        // msg: wave-per-edge; src indices via readlane; scalar-skip dead slots
        for (int le = wave; le < nE; le += NW) {
            int sv = srcL[le * DMAX + (lane & 7)];
            float e2b0 = __bfloat162float(beB[(size_t)(s0 + le) * 128 + lane]);
            float e2b1 = __bfloat162float(beB[(size_t)(s0 + le) * 128 + 64 + lane]);
            float sw0 = 0.f, swr0 = 0.f, sw1 = 0.f, swr1 = 0.f;
            bool anyV = false;
            #pragma unroll
            for (int d = 0; d < DMAX; ++d) {
                int ls = __builtin_amdgcn_readlane(sv, d);
                if (ls >= 0) {
                    anyV = true;
                    unsigned pk0 = MaMeL[ls * 128 + lane];
                    unsigned pk1 = MaMeL[ls * 128 + 64 + lane];
                    float w0 = __uint_as_float(pk0 << 16);
                    float m0 = __uint_as_float(pk0 & 0xFFFF0000u);
                    float w1 = __uint_as_float(pk1 << 16);
                    float m1 = __uint_as_float(pk1 & 0xFFFF0000u);
                    sw0 += w0;
                    swr0 = fmaf(w0, __builtin_amdgcn_rcpf(fmaf(e2b0, m0, 1.f)), swr0);
                    sw1 += w1;
                    swr1 = fmaf(w1, __builtin_amdgcn_rcpf(fmaf(e2b1, m1, 1.f)), swr1);
                }
            }
            float r0 = anyV ? swr0 * __builtin_amdgcn_rcpf(sw0)
                            : __builtin_amdgcn_rcpf(e2b0 + 1.f);
            float r1 = anyV ? swr1 * __builtin_amdgcn_rcpf(sw1)
                            : __builtin_amdgcn_rcpf(e2b1 + 1.f);
            float v0 = fmaf(-2.f, r0, 1.f);
            float v1 = fmaf(-2.f, r1, 1.f);
            if (step == 0) {
                memL[le * MSTR + lane] = __float2bfloat16(v0);
                memL[le * MSTR + 64 + lane] = __float2bfloat16(v1);
            } else {           // final step: scatter straight into node sums
                int v = __builtin_amdgcn_readfirstlane(nodeL[le]);
                atomicAdd(&nsF[v * 128 + lane], v0);
                atomicAdd(&nsF[v * 128 + 64 + lane], v1);
            }
        }
        __syncthreads();
    }

    // nsF -> bf16 nsbL (pads zero)
    for (int idx = tid; idx < 48 * 128; idx += NT) {
        int v = idx >> 7, k = idx & 127;
        nsbL[v * MSTR + k] = __float2bfloat16(v < VN ? nsF[idx] : 0.f);
    }
    __syncthreads();
    // GO = nsb @ Wt3 + bias : 48 tiles; epilogue packs {exp(att), exp(2*emb)}
    for (int t = wave; t < 48; t += NW) {
        int r = t >> 4;
        int col0 = (t & 15) * 16;
        short8 Af[4], Bg[4];
        #pragma unroll
        for (int kb = 0; kb < 4; ++kb) {
            Af[kb] = *(const short8*)((const short*)nsbL + (r * 16 + lm) * MSTR + kb * 32 + lq * 8);
            Bg[kb] = *(const short8*)((const short*)Wt3 + (size_t)(col0 + lm) * 128 + kb * 32 + lq * 8);
        }
        f32x4 acc = {0.f, 0.f, 0.f, 0.f};
        #pragma unroll
        for (int kb = 0; kb < 4; ++kb)
            acc = __builtin_amdgcn_mfma_f32_16x16x32_bf16(Af[kb], Bg[kb], acc, 0, 0, 0);
        int col = col0 + lm;
        int cc = col & 127;
        float bv = (col < 128) ? bg_att[col] : bg_emb[cc];
        __hip_bfloat16* hp = (__hip_bfloat16*)GOLp;
        if (col < 128) {
            #pragma unroll
            for (int i2 = 0; i2 < 4; ++i2)
                hp[((r * 16 + lq * 4 + i2) * 128 + cc) * 2] =
                    __float2bfloat16(__expf(acc[i2] + bv));
        } else {
            #pragma unroll
            for (int i2 = 0; i2 < 4; ++i2)
                hp[((r * 16 + lq * 4 + i2) * 128 + cc) * 2 + 1] =
                    __float2bfloat16(__expf(2.f * (acc[i2] + bv)));
        }
    }
    __syncthreads();
    // node softmax: 8-way v-split; gemb = 1 - 2*Σ(w*r)/Σw
    {
        int c = tid & 127, q = tid >> 7;
        float sw = 0.f, swr = 0.f;
        for (int v = q; v < VN; v += 8) {
            if (nmL[v] == 0.f) continue;
            unsigned pk = GOLp[v * 128 + c];
            float w = __uint_as_float(pk << 16);
            float e2 = __uint_as_float(pk & 0xFFFF0000u);
            sw += w;
            swr = fmaf(w, __builtin_amdgcn_rcpf(e2 + 1.f), swr);
        }
        numP[tid] = swr;
        denP[tid] = sw;
    }
    __syncthreads();
    if (tid < 128) {
        float swr = 0.f, sw = 0.f;
        #pragma unroll
        for (int p = 0; p < 8; ++p) { swr += numP[p * 128 + tid]; sw += denP[p * 128 + tid]; }
        gembL[tid] = fmaf(-2.f, swr / sw, 1.f);
    }
    __syncthreads();
    // out = gemb @ W_out + b_out (8-way j-split)
    {
        int c = tid & 127, h = tid >> 7;
        float acc = 0.f;
        for (int j = h; j < 128; j += 8)
            acc += gembL[j] * W_out[j * OUTD + c];
        redL[tid] = acc;
    }
    __syncthreads();
    if (tid < 128) {
        float acc = b_out[tid];
        #pragma unroll
        for (int p = 0; p < 8; ++p) acc += redL[p * 128 + tid];
        out[(size_t)b * OUTD + tid] = acc;
    }
}

extern "C" void kernel_launch(void* const* d_in, const int* in_sizes, int n_in,
                              void* d_out, int out_size, void* d_ws, size_t ws_size,
                              hipStream_t stream) {
    const float* nodes    = (const float*)d_in[0];
    const float* edges    = (const float*)d_in[1];
    const float* W_pre    = (const float*)d_in[2];
    const float* b_pre    = (const float*)d_in[3];
    const float* W_att    = (const float*)d_in[4];
    const float* W_emb    = (const float*)d_in[6];
    const float* b_emb    = (const float*)d_in[7];
    const float* Wg_att   = (const float*)d_in[8];
    const float* bg_att   = (const float*)d_in[9];
    const float* Wg_emb   = (const float*)d_in[10];
    const float* bg_emb   = (const float*)d_in[11];
    const float* W_out    = (const float*)d_in[12];
    const float* b_out    = (const float*)d_in[13];
    const float* node_mask = (const float*)d_in[15];
    const int* eb_b   = (const int*)d_in[16];
    const int* eb_n   = (const int*)d_in[17];
    const int* eb_nb  = (const int*)d_in[18];
    const int* in_eb  = (const int*)d_in[19];
    const int* in_igeb = (const int*)d_in[20];
    const int* in_ige  = (const int*)d_in[21];

    int E = in_sizes[16];
    int K = in_sizes[19];
    int E64 = (E + 63) & ~63;

    __hip_bfloat16* Wt1 = (__hip_bfloat16*)d_ws;              // 128*128
    __hip_bfloat16* Wt2 = Wt1 + 128 * 128;                    // 256*128
    __hip_bfloat16* Wt3 = Wt2 + 256 * 128;                    // 256*128
    __hip_bfloat16* Wpt = Wt3 + 256 * 128;                    // 128*WPSTR
    __hip_bfloat16* beB = Wpt + 128 * WPSTR;                  // (E64+128)*128
    int* off  = (int*)(beB + (size_t)(E64 + 128) * 128);      // NN+1
    int* eoff = off + (NN + 1);                               // E+1

    int nbO = (E + 255) / 256;
    int nbK = (K + 255) / 256;

    k_setup<<<nbO + nbK + 128, 256, 0, stream>>>(in_igeb, eb_b,
                                                 W_att, W_emb, Wg_att, Wg_emb, W_pre,
                                                 off, eoff, Wt1, Wt2, Wt3, Wpt,
                                                 K, E, nbO, nbK);
    k_pre2<<<E64 / 64, 256, 0, stream>>>(nodes, edges, Wpt, b_pre,
                                         eb_b, eb_n, eb_nb, Wt1, b_emb, beB, E);
    k_mp<<<NN, NT, 0, stream>>>(beB, Wt2, Wt3, bg_att, bg_emb,
                                in_igeb, in_ige, in_eb, eoff, eb_n, node_mask,
                                W_out, b_out, off, (float*)d_out);
}